// Round 1
// baseline (420.686 us; speedup 1.0000x reference)
//
#include <hip/hip_runtime.h>
#include <cfloat>
#include <cmath>

#define N_TOK (32*4096)                 // 131072 tokens
#define DIM   64
#define N_E   1024
#define NPART 4
#define CODES_PER_PART (N_E / NPART)    // 256
#define KCHUNK 128

// ws layout (bytes)
#define WS_CNORM   0u
#define WS_PSCORE  4096u
#define WS_PIDX    (4096u + 2097152u)
#define WS_IDX     (WS_PIDX + 2097152u)
#define WS_COUNTS  (WS_IDX + 524288u)
#define WS_SSE     (WS_COUNTS + 4096u)

__global__ __launch_bounds__(256) void cnorm_kernel(const float* __restrict__ cb,
                                                    float* __restrict__ cnorm) {
    int k = blockIdx.x * 256 + threadIdx.x;
    if (k < N_E) {
        const float4* c4 = (const float4*)(cb + (size_t)k * DIM);
        float a0 = 0.f, a1 = 0.f, a2 = 0.f, a3 = 0.f;
#pragma unroll
        for (int i = 0; i < 4; ++i) {
            float4 v0 = c4[i*4+0], v1 = c4[i*4+1], v2 = c4[i*4+2], v3 = c4[i*4+3];
            a0 += v0.x*v0.x + v0.y*v0.y + v0.z*v0.z + v0.w*v0.w;
            a1 += v1.x*v1.x + v1.y*v1.y + v1.z*v1.z + v1.w*v1.w;
            a2 += v2.x*v2.x + v2.y*v2.y + v2.z*v2.z + v2.w*v2.w;
            a3 += v3.x*v3.x + v3.y*v3.y + v3.z*v3.z + v3.w*v3.w;
        }
        cnorm[k] = (a0 + a1) + (a2 + a3);
    }
}

// score_k = ||e_k||^2 - 2*z.e_k  (argmin same as full d; ||z||^2 omitted on purpose)
__global__ __launch_bounds__(256, 3) void argmin_kernel(const float* __restrict__ z,
        const float* __restrict__ cb, const float* __restrict__ cnorm,
        float* __restrict__ pscore, int* __restrict__ pidx) {
    __shared__ float lds_cb[KCHUNK * DIM];   // 32 KB
    __shared__ float lds_cn[KCHUNK];
    const int t = threadIdx.x;
    const int g = blockIdx.x >> 2;           // token group (0..255), 512 tokens each
    const int h = blockIdx.x & 3;            // code quarter
    const int tok0 = g * 512 + t;
    const int tok1 = tok0 + 256;
    const float4* z4 = (const float4*)z;
    float4 za[16], zb[16];
#pragma unroll
    for (int i = 0; i < 16; ++i) za[i] = z4[(size_t)tok0 * 16 + i];
#pragma unroll
    for (int i = 0; i < 16; ++i) zb[i] = z4[(size_t)tok1 * 16 + i];

    float bestA = FLT_MAX, bestB = FLT_MAX;
    int ia = 0, ib = 0;

    for (int c = 0; c < CODES_PER_PART; c += KCHUNK) {
        const int cbase = h * CODES_PER_PART + c;
        __syncthreads();
        const float4* src = (const float4*)cb + (size_t)cbase * 16;
        float4* dst = (float4*)lds_cb;
#pragma unroll
        for (int i = 0; i < 8; ++i) dst[t + 256 * i] = src[t + 256 * i];
        if (t < KCHUNK) lds_cn[t] = cnorm[cbase + t];
        __syncthreads();

        for (int k = 0; k < KCHUNK; ++k) {
            const float4* e4 = (const float4*)(lds_cb + k * DIM);
            float a0=0.f,a1=0.f,a2=0.f,a3=0.f,b0=0.f,b1=0.f,b2=0.f,b3=0.f;
#pragma unroll
            for (int i = 0; i < 4; ++i) {
                float4 e0 = e4[i*4+0], e1 = e4[i*4+1], e2 = e4[i*4+2], e3 = e4[i*4+3];
                float4 x0 = za[i*4+0], x1 = za[i*4+1], x2 = za[i*4+2], x3 = za[i*4+3];
                float4 y0 = zb[i*4+0], y1 = zb[i*4+1], y2 = zb[i*4+2], y3 = zb[i*4+3];
                a0 = fmaf(x0.x,e0.x, fmaf(x0.y,e0.y, fmaf(x0.z,e0.z, fmaf(x0.w,e0.w, a0))));
                a1 = fmaf(x1.x,e1.x, fmaf(x1.y,e1.y, fmaf(x1.z,e1.z, fmaf(x1.w,e1.w, a1))));
                a2 = fmaf(x2.x,e2.x, fmaf(x2.y,e2.y, fmaf(x2.z,e2.z, fmaf(x2.w,e2.w, a2))));
                a3 = fmaf(x3.x,e3.x, fmaf(x3.y,e3.y, fmaf(x3.z,e3.z, fmaf(x3.w,e3.w, a3))));
                b0 = fmaf(y0.x,e0.x, fmaf(y0.y,e0.y, fmaf(y0.z,e0.z, fmaf(y0.w,e0.w, b0))));
                b1 = fmaf(y1.x,e1.x, fmaf(y1.y,e1.y, fmaf(y1.z,e1.z, fmaf(y1.w,e1.w, b1))));
                b2 = fmaf(y2.x,e2.x, fmaf(y2.y,e2.y, fmaf(y2.z,e2.z, fmaf(y2.w,e2.w, b2))));
                b3 = fmaf(y3.x,e3.x, fmaf(y3.y,e3.y, fmaf(y3.z,e3.z, fmaf(y3.w,e3.w, b3))));
            }
            float dA = (a0 + a1) + (a2 + a3);
            float dB = (b0 + b1) + (b2 + b3);
            float cn = lds_cn[k];
            float sA = fmaf(-2.f, dA, cn);
            float sB = fmaf(-2.f, dB, cn);
            int kk = cbase + k;
            if (sA < bestA) { bestA = sA; ia = kk; }   // strict <  => first-min tie rule
            if (sB < bestB) { bestB = sB; ib = kk; }
        }
    }
    pscore[(size_t)h * N_TOK + tok0] = bestA;
    pscore[(size_t)h * N_TOK + tok1] = bestB;
    pidx[(size_t)h * N_TOK + tok0] = ia;
    pidx[(size_t)h * N_TOK + tok1] = ib;
}

__global__ __launch_bounds__(256) void merge_kernel(const float* __restrict__ ps,
        const int* __restrict__ pi, int* __restrict__ idx) {
    int tok = blockIdx.x * 256 + threadIdx.x;
    float best = ps[tok];
    int bi = pi[tok];
#pragma unroll
    for (int h = 1; h < NPART; ++h) {
        float s = ps[(size_t)h * N_TOK + tok];
        int i2 = pi[(size_t)h * N_TOK + tok];
        if (s < best) { best = s; bi = i2; }   // ties keep lower code quarter
    }
    idx[tok] = bi;
}

__global__ __launch_bounds__(256) void gather_kernel(const float* __restrict__ z,
        const float* __restrict__ cb, const int* __restrict__ idx,
        float* __restrict__ out, unsigned* __restrict__ counts,
        float* __restrict__ sse) {
    const int lane = threadIdx.x & 63;
    const int wid = (blockIdx.x * 256 + threadIdx.x) >> 6;   // 1024 waves
    float acc = 0.f;
    for (int tok = wid; tok < N_TOK; tok += 1024) {
        int id = idx[tok];
        float q = cb[(size_t)id * DIM + lane];
        float zv = z[(size_t)tok * DIM + lane];
        out[1 + (size_t)tok * DIM + lane] = q;
        float d = q - zv;
        acc = fmaf(d, d, acc);
        if (lane == 0) atomicAdd(&counts[id], 1u);
    }
#pragma unroll
    for (int off = 32; off; off >>= 1) acc += __shfl_down(acc, off);
    if (lane == 0) atomicAdd(sse, acc);
}

__global__ __launch_bounds__(256) void finalize_kernel(const unsigned* __restrict__ counts,
        const float* __restrict__ sse, float* __restrict__ out) {
    __shared__ float red[4];
    int t = threadIdx.x;
    float acc = 0.f;
#pragma unroll
    for (int i = 0; i < 4; ++i) {
        float p = (float)counts[t + 256 * i] * (1.0f / 131072.0f);
        acc += p * logf(p + 1e-10f);
    }
#pragma unroll
    for (int off = 32; off; off >>= 1) acc += __shfl_down(acc, off);
    if ((t & 63) == 0) red[t >> 6] = acc;
    __syncthreads();
    if (t == 0) {
        float H = -((red[0] + red[1]) + (red[2] + red[3]));
        out[0] = 1.25f * sse[0] * (1.0f / 8388608.0f);   // (1+BETA)*MSE
        out[8388609] = expf(H);
    }
}

extern "C" void kernel_launch(void* const* d_in, const int* in_sizes, int n_in,
                              void* d_out, int out_size, void* d_ws, size_t ws_size,
                              hipStream_t stream) {
    const float* z  = (const float*)d_in[0];
    const float* cb = (const float*)d_in[1];
    float* out = (float*)d_out;
    char* ws = (char*)d_ws;
    float*    cnorm  = (float*)(ws + WS_CNORM);
    float*    pscore = (float*)(ws + WS_PSCORE);
    int*      pidx   = (int*)(ws + WS_PIDX);
    int*      idx    = (int*)(ws + WS_IDX);
    unsigned* counts = (unsigned*)(ws + WS_COUNTS);
    float*    sse    = (float*)(ws + WS_SSE);

    hipMemsetAsync(ws + WS_COUNTS, 0, 4096 + 256, stream);
    cnorm_kernel<<<4, 256, 0, stream>>>(cb, cnorm);
    argmin_kernel<<<1024, 256, 0, stream>>>(z, cb, cnorm, pscore, pidx);
    merge_kernel<<<512, 256, 0, stream>>>(pscore, pidx, idx);
    gather_kernel<<<256, 256, 0, stream>>>(z, cb, idx, out, counts, sse);
    finalize_kernel<<<1, 256, 0, stream>>>(counts, sse, out);
}

// Round 2
// 230.037 us; speedup vs baseline: 1.8288x; 1.8288x over previous
//
#include <hip/hip_runtime.h>
#include <cfloat>
#include <cmath>

#define N_TOK (32*4096)                 // 131072 tokens
#define DIM   64
#define N_E   1024
#define CSTRIDE 74                      // bf16 elems per LDS code row (64 + 10 pad -> ~2-way banks)

typedef __attribute__((ext_vector_type(8))) __bf16 bf16x8;
typedef __attribute__((ext_vector_type(4))) float  f32x4;

// ws layout (bytes)
#define WS_CN     0u                    // 1024 f32              (4 KB)
#define WS_CBH    4096u                 // 1024*64 bf16 hi       (128 KB)
#define WS_CBL    135168u               // 1024*64 bf16 lo       (128 KB)
#define WS_IDX    266240u               // 131072 int            (512 KB)
#define WS_COUNTS 790528u               // 1024 u32              (4 KB)
#define WS_SSE    794624u               // 1 f32

// Compute code norms and split codebook into bf16 hi/lo planes.
__global__ __launch_bounds__(256) void prep_kernel(const float* __restrict__ cb,
        float* __restrict__ cn, __bf16* __restrict__ cbh, __bf16* __restrict__ cbl) {
    int k = blockIdx.x * 256 + threadIdx.x;          // 0..1023
    const float4* c4 = (const float4*)(cb + (size_t)k * DIM);
    bf16x8* ph = (bf16x8*)(cbh + (size_t)k * DIM);
    bf16x8* pl = (bf16x8*)(cbl + (size_t)k * DIM);
    float nrm = 0.f;
#pragma unroll
    for (int o = 0; o < 8; ++o) {
        float4 a = c4[o*2], b = c4[o*2+1];
        float v[8] = {a.x,a.y,a.z,a.w,b.x,b.y,b.z,b.w};
        bf16x8 hv, lv;
#pragma unroll
        for (int j = 0; j < 8; ++j) {
            float f = v[j];
            nrm = fmaf(f, f, nrm);
            __bf16 h = (__bf16)f;
            __bf16 l = (__bf16)(f - (float)h);
            hv[j] = h; lv[j] = l;
        }
        ph[o] = hv; pl[o] = lv;
    }
    cn[k] = nrm;
}

// score_k = ||e_k||^2 - 2*z.e_k via 3-pass bf16-split MFMA; ||z||^2 omitted (argmin-invariant).
__global__ __launch_bounds__(256, 2) void argmin_kernel(const float* __restrict__ z,
        const __bf16* __restrict__ cbh, const __bf16* __restrict__ cbl,
        const float* __restrict__ cn, int* __restrict__ idx_out) {
    __shared__ __bf16 lh[128 * CSTRIDE];             // 18944 B
    __shared__ __bf16 ll[128 * CSTRIDE];             // 18944 B
    __shared__ float  lcn[128];
    const int t    = threadIdx.x;
    const int lane = t & 63;
    const int w    = t >> 6;
    const int n    = lane & 15;                      // MFMA col / B-row
    const int q    = lane >> 4;                      // k-octet selector
    const int wtok = blockIdx.x * 256 + w * 64;

    // A fragments (64 tokens/wave as 4 tiles x 2 K-halves), bf16 hi/lo in regs.
    bf16x8 ah[4][2], al[4][2];
    const float4* z4 = (const float4*)z;
#pragma unroll
    for (int tile = 0; tile < 4; ++tile) {
        int tok = wtok + tile*16 + n;
#pragma unroll
        for (int kf = 0; kf < 2; ++kf) {
            float4 p0 = z4[(size_t)tok*16 + kf*8 + q*2];
            float4 p1 = z4[(size_t)tok*16 + kf*8 + q*2 + 1];
            float v[8] = {p0.x,p0.y,p0.z,p0.w,p1.x,p1.y,p1.z,p1.w};
            bf16x8 hv, lv;
#pragma unroll
            for (int j = 0; j < 8; ++j) {
                __bf16 h = (__bf16)v[j];
                __bf16 l = (__bf16)(v[j] - (float)h);
                hv[j] = h; lv[j] = l;
            }
            ah[tile][kf] = hv; al[tile][kf] = lv;
        }
    }

    float best[16]; int bidx[16];
#pragma unroll
    for (int s = 0; s < 16; ++s) { best[s] = FLT_MAX; bidx[s] = 0; }

    for (int cblk = 0; cblk < 8; ++cblk) {
        const int cbase = cblk * 128;
        __syncthreads();
#pragma unroll
        for (int i = 0; i < 4; ++i) {
            int gi = t + 256*i;                      // 0..1023
            int row = gi >> 3, oct = gi & 7;
            const bf16x8* gh = (const bf16x8*)(cbh + (size_t)(cbase+row)*DIM);
            const bf16x8* gl = (const bf16x8*)(cbl + (size_t)(cbase+row)*DIM);
            *(bf16x8*)(lh + row*CSTRIDE + oct*8) = gh[oct];
            *(bf16x8*)(ll + row*CSTRIDE + oct*8) = gl[oct];
        }
        if (t < 128) lcn[t] = cn[cbase + t];
        __syncthreads();

        for (int ch = 0; ch < 8; ++ch) {
            const int rb = ch*16 + n;
            bf16x8 bh0 = *(const bf16x8*)(lh + rb*CSTRIDE + q*8);
            bf16x8 bh1 = *(const bf16x8*)(lh + rb*CSTRIDE + 32 + q*8);
            bf16x8 bl0 = *(const bf16x8*)(ll + rb*CSTRIDE + q*8);
            bf16x8 bl1 = *(const bf16x8*)(ll + rb*CSTRIDE + 32 + q*8);
            float cnv = lcn[ch*16 + n];
            int  code = cbase + ch*16 + n;
#pragma unroll
            for (int tile = 0; tile < 4; ++tile) {
                f32x4 acc = {0.f, 0.f, 0.f, 0.f};
                acc = __builtin_amdgcn_mfma_f32_16x16x32_bf16(ah[tile][0], bh0, acc, 0, 0, 0);
                acc = __builtin_amdgcn_mfma_f32_16x16x32_bf16(ah[tile][1], bh1, acc, 0, 0, 0);
                acc = __builtin_amdgcn_mfma_f32_16x16x32_bf16(al[tile][0], bh0, acc, 0, 0, 0);
                acc = __builtin_amdgcn_mfma_f32_16x16x32_bf16(al[tile][1], bh1, acc, 0, 0, 0);
                acc = __builtin_amdgcn_mfma_f32_16x16x32_bf16(ah[tile][0], bl0, acc, 0, 0, 0);
                acc = __builtin_amdgcn_mfma_f32_16x16x32_bf16(ah[tile][1], bl1, acc, 0, 0, 0);
#pragma unroll
                for (int r = 0; r < 4; ++r) {
                    float s = fmaf(-2.f, acc[r], cnv);
                    int slot = tile*4 + r;
                    if (s < best[slot]) { best[slot] = s; bidx[slot] = code; }  // strict <: first-min
                }
            }
        }
    }

    // cross-lane argmin over the 16 code-columns (lanes sharing q-group), index tiebreak low.
#pragma unroll
    for (int s = 0; s < 16; ++s) {
        float bs = best[s]; int bi = bidx[s];
#pragma unroll
        for (int m = 8; m >= 1; m >>= 1) {
            float s2 = __shfl_xor(bs, m, 64);
            int   i2 = __shfl_xor(bi, m, 64);
            if (s2 < bs || (s2 == bs && i2 < bi)) { bs = s2; bi = i2; }
        }
        if (n == 0) {
            int tok = wtok + (s >> 2)*16 + q*4 + (s & 3);   // tile*16 + row
            idx_out[tok] = bi;
        }
    }
}

__global__ __launch_bounds__(256) void gather_kernel(const float* __restrict__ z,
        const float* __restrict__ cb, const int* __restrict__ idx,
        float* __restrict__ out, unsigned* __restrict__ counts,
        float* __restrict__ sse) {
    const int lane = threadIdx.x & 63;
    const int wid = (blockIdx.x * 256 + threadIdx.x) >> 6;   // 0..4095
    float acc = 0.f;
    for (int tok = wid; tok < N_TOK; tok += 4096) {
        int id = idx[tok];
        float qv = cb[(size_t)id * DIM + lane];
        float zv = z[(size_t)tok * DIM + lane];
        out[1 + (size_t)tok * DIM + lane] = qv;
        float d = qv - zv;
        acc = fmaf(d, d, acc);
        if (lane == 0) atomicAdd(&counts[id], 1u);
    }
#pragma unroll
    for (int off = 32; off; off >>= 1) acc += __shfl_down(acc, off, 64);
    if (lane == 0) atomicAdd(sse, acc);
}

__global__ __launch_bounds__(256) void finalize_kernel(const unsigned* __restrict__ counts,
        const float* __restrict__ sse, float* __restrict__ out) {
    __shared__ float red[4];
    int t = threadIdx.x;
    float acc = 0.f;
#pragma unroll
    for (int i = 0; i < 4; ++i) {
        float p = (float)counts[t + 256*i] * (1.0f / 131072.0f);
        acc += p * logf(p + 1e-10f);
    }
#pragma unroll
    for (int off = 32; off; off >>= 1) acc += __shfl_down(acc, off, 64);
    if ((t & 63) == 0) red[t >> 6] = acc;
    __syncthreads();
    if (t == 0) {
        float H = -((red[0] + red[1]) + (red[2] + red[3]));
        out[0] = 1.25f * sse[0] * (1.0f / 8388608.0f);   // (1+BETA)*MSE
        out[8388609] = expf(H);
    }
}

extern "C" void kernel_launch(void* const* d_in, const int* in_sizes, int n_in,
                              void* d_out, int out_size, void* d_ws, size_t ws_size,
                              hipStream_t stream) {
    const float* z  = (const float*)d_in[0];
    const float* cb = (const float*)d_in[1];
    float* out = (float*)d_out;
    char* ws = (char*)d_ws;
    float*    cn     = (float*)(ws + WS_CN);
    __bf16*   cbh    = (__bf16*)(ws + WS_CBH);
    __bf16*   cbl    = (__bf16*)(ws + WS_CBL);
    int*      idx    = (int*)(ws + WS_IDX);
    unsigned* counts = (unsigned*)(ws + WS_COUNTS);
    float*    sse    = (float*)(ws + WS_SSE);

    hipMemsetAsync(ws + WS_COUNTS, 0, 4096 + 4, stream);
    prep_kernel<<<4, 256, 0, stream>>>(cb, cn, cbh, cbl);
    argmin_kernel<<<512, 256, 0, stream>>>(z, cbh, cbl, cn, idx);
    gather_kernel<<<1024, 256, 0, stream>>>(z, cb, idx, out, counts, sse);
    finalize_kernel<<<1, 256, 0, stream>>>(counts, sse, out);
}

// Round 3
// 199.575 us; speedup vs baseline: 2.1079x; 1.1526x over previous
//
#include <hip/hip_runtime.h>
#include <cfloat>
#include <cmath>

#define N_TOK (32*4096)                 // 131072 tokens
#define DIM   64
#define N_E   1024
#define CSTRIDE 74                      // bf16 elems per LDS code row (64 + 10 pad -> ~2-way banks)

typedef __attribute__((ext_vector_type(8))) __bf16 bf16x8;
typedef __attribute__((ext_vector_type(4))) float  f32x4;

// ws layout (bytes)
#define WS_CN     0u                    // 1024 f32              (4 KB)
#define WS_CBH    4096u                 // 1024*64 bf16 hi       (128 KB)
#define WS_CBL    135168u               // 1024*64 bf16 lo       (128 KB)
#define WS_IDX    266240u               // 131072 int            (512 KB)
#define WS_COUNTS 790528u               // 1024 u32              (4 KB)
#define WS_SSE    794624u               // 1 f32

// Compute code norms and split codebook into bf16 hi/lo planes.
__global__ __launch_bounds__(256) void prep_kernel(const float* __restrict__ cb,
        float* __restrict__ cn, __bf16* __restrict__ cbh, __bf16* __restrict__ cbl) {
    int k = blockIdx.x * 256 + threadIdx.x;          // 0..1023
    const float4* c4 = (const float4*)(cb + (size_t)k * DIM);
    bf16x8* ph = (bf16x8*)(cbh + (size_t)k * DIM);
    bf16x8* pl = (bf16x8*)(cbl + (size_t)k * DIM);
    float nrm = 0.f;
#pragma unroll
    for (int o = 0; o < 8; ++o) {
        float4 a = c4[o*2], b = c4[o*2+1];
        float v[8] = {a.x,a.y,a.z,a.w,b.x,b.y,b.z,b.w};
        bf16x8 hv, lv;
#pragma unroll
        for (int j = 0; j < 8; ++j) {
            float f = v[j];
            nrm = fmaf(f, f, nrm);
            __bf16 h = (__bf16)f;
            __bf16 l = (__bf16)(f - (float)h);
            hv[j] = h; lv[j] = l;
        }
        ph[o] = hv; pl[o] = lv;
    }
    cn[k] = nrm;
}

// score_k = ||e_k||^2 - 2*z.e_k via 3-pass bf16-split MFMA; ||z||^2 omitted (argmin-invariant).
__global__ __launch_bounds__(256, 2) void argmin_kernel(const float* __restrict__ z,
        const __bf16* __restrict__ cbh, const __bf16* __restrict__ cbl,
        const float* __restrict__ cn, int* __restrict__ idx_out) {
    __shared__ __bf16 lh[128 * CSTRIDE];             // 18944 B
    __shared__ __bf16 ll[128 * CSTRIDE];             // 18944 B
    __shared__ float  lcn[128];
    const int t    = threadIdx.x;
    const int lane = t & 63;
    const int w    = t >> 6;
    const int n    = lane & 15;                      // MFMA col / B-row
    const int q    = lane >> 4;                      // k-octet selector
    const int wtok = blockIdx.x * 256 + w * 64;

    // A fragments (64 tokens/wave as 4 tiles x 2 K-halves), bf16 hi/lo in regs.
    bf16x8 ah[4][2], al[4][2];
    const float4* z4 = (const float4*)z;
#pragma unroll
    for (int tile = 0; tile < 4; ++tile) {
        int tok = wtok + tile*16 + n;
#pragma unroll
        for (int kf = 0; kf < 2; ++kf) {
            float4 p0 = z4[(size_t)tok*16 + kf*8 + q*2];
            float4 p1 = z4[(size_t)tok*16 + kf*8 + q*2 + 1];
            float v[8] = {p0.x,p0.y,p0.z,p0.w,p1.x,p1.y,p1.z,p1.w};
            bf16x8 hv, lv;
#pragma unroll
            for (int j = 0; j < 8; ++j) {
                __bf16 h = (__bf16)v[j];
                __bf16 l = (__bf16)(v[j] - (float)h);
                hv[j] = h; lv[j] = l;
            }
            ah[tile][kf] = hv; al[tile][kf] = lv;
        }
    }

    float best[16]; int bidx[16];
#pragma unroll
    for (int s = 0; s < 16; ++s) { best[s] = FLT_MAX; bidx[s] = 0; }

    for (int cblk = 0; cblk < 8; ++cblk) {
        const int cbase = cblk * 128;
        __syncthreads();
#pragma unroll
        for (int i = 0; i < 4; ++i) {
            int gi = t + 256*i;                      // 0..1023
            int row = gi >> 3, oct = gi & 7;
            const bf16x8* gh = (const bf16x8*)(cbh + (size_t)(cbase+row)*DIM);
            const bf16x8* gl = (const bf16x8*)(cbl + (size_t)(cbase+row)*DIM);
            *(bf16x8*)(lh + row*CSTRIDE + oct*8) = gh[oct];
            *(bf16x8*)(ll + row*CSTRIDE + oct*8) = gl[oct];
        }
        if (t < 128) lcn[t] = cn[cbase + t];
        __syncthreads();

        for (int ch = 0; ch < 8; ++ch) {
            const int rb = ch*16 + n;
            bf16x8 bh0 = *(const bf16x8*)(lh + rb*CSTRIDE + q*8);
            bf16x8 bh1 = *(const bf16x8*)(lh + rb*CSTRIDE + 32 + q*8);
            bf16x8 bl0 = *(const bf16x8*)(ll + rb*CSTRIDE + q*8);
            bf16x8 bl1 = *(const bf16x8*)(ll + rb*CSTRIDE + 32 + q*8);
            float cnv = lcn[ch*16 + n];
            int  code = cbase + ch*16 + n;
#pragma unroll
            for (int tile = 0; tile < 4; ++tile) {
                f32x4 acc = {0.f, 0.f, 0.f, 0.f};
                acc = __builtin_amdgcn_mfma_f32_16x16x32_bf16(ah[tile][0], bh0, acc, 0, 0, 0);
                acc = __builtin_amdgcn_mfma_f32_16x16x32_bf16(ah[tile][1], bh1, acc, 0, 0, 0);
                acc = __builtin_amdgcn_mfma_f32_16x16x32_bf16(al[tile][0], bh0, acc, 0, 0, 0);
                acc = __builtin_amdgcn_mfma_f32_16x16x32_bf16(al[tile][1], bh1, acc, 0, 0, 0);
                acc = __builtin_amdgcn_mfma_f32_16x16x32_bf16(ah[tile][0], bl0, acc, 0, 0, 0);
                acc = __builtin_amdgcn_mfma_f32_16x16x32_bf16(ah[tile][1], bl1, acc, 0, 0, 0);
#pragma unroll
                for (int r = 0; r < 4; ++r) {
                    float s = fmaf(-2.f, acc[r], cnv);
                    int slot = tile*4 + r;
                    if (s < best[slot]) { best[slot] = s; bidx[slot] = code; }  // strict <: first-min
                }
            }
        }
    }

    // cross-lane argmin over the 16 code-columns (lanes sharing q-group), index tiebreak low.
#pragma unroll
    for (int s = 0; s < 16; ++s) {
        float bs = best[s]; int bi = bidx[s];
#pragma unroll
        for (int m = 8; m >= 1; m >>= 1) {
            float s2 = __shfl_xor(bs, m, 64);
            int   i2 = __shfl_xor(bi, m, 64);
            if (s2 < bs || (s2 == bs && i2 < bi)) { bs = s2; bi = i2; }
        }
        if (n == 0) {
            int tok = wtok + (s >> 2)*16 + q*4 + (s & 3);   // tile*16 + row
            idx_out[tok] = bi;
        }
    }
}

// Latency-optimized gather: wave owns 16 contiguous tokens; indices batch-loaded
// by lanes 0..15 in ONE instruction, broadcast via readlane -> all 32 row loads
// independent and in flight together. 8192 waves = 32 waves/CU.
__global__ __launch_bounds__(256) void gather_kernel(const float* __restrict__ z,
        const float* __restrict__ cb, const int* __restrict__ idx,
        float* __restrict__ out, unsigned* __restrict__ counts,
        float* __restrict__ sse) {
    const int lane = threadIdx.x & 63;
    const int w    = threadIdx.x >> 6;
    const int wid  = blockIdx.x * 4 + w;            // 0..8191
    const int base = wid * 16;

    int myidx = 0;
    if (lane < 16) myidx = idx[base + lane];

    float acc = 0.f;
#pragma unroll
    for (int i = 0; i < 16; ++i) {
        int id  = __shfl(myidx, i, 64);             // compile-time lane -> v_readlane (SGPR)
        int tok = base + i;
        float qv = cb[(size_t)id * DIM + lane];
        float zv = z[(size_t)tok * DIM + lane];
        out[1 + (size_t)tok * DIM + lane] = qv;
        float d = qv - zv;
        acc = fmaf(d, d, acc);
        if (lane == 0) atomicAdd(&counts[id], 1u);
    }
#pragma unroll
    for (int off = 32; off; off >>= 1) acc += __shfl_down(acc, off, 64);
    __shared__ float red[4];
    if (lane == 0) red[w] = acc;
    __syncthreads();
    if (threadIdx.x == 0) atomicAdd(sse, (red[0] + red[1]) + (red[2] + red[3]));
}

__global__ __launch_bounds__(256) void finalize_kernel(const unsigned* __restrict__ counts,
        const float* __restrict__ sse, float* __restrict__ out) {
    __shared__ float red[4];
    int t = threadIdx.x;
    float acc = 0.f;
#pragma unroll
    for (int i = 0; i < 4; ++i) {
        float p = (float)counts[t + 256*i] * (1.0f / 131072.0f);
        acc += p * logf(p + 1e-10f);
    }
#pragma unroll
    for (int off = 32; off; off >>= 1) acc += __shfl_down(acc, off, 64);
    if ((t & 63) == 0) red[t >> 6] = acc;
    __syncthreads();
    if (t == 0) {
        float H = -((red[0] + red[1]) + (red[2] + red[3]));
        out[0] = 1.25f * sse[0] * (1.0f / 8388608.0f);   // (1+BETA)*MSE
        out[8388609] = expf(H);
    }
}

extern "C" void kernel_launch(void* const* d_in, const int* in_sizes, int n_in,
                              void* d_out, int out_size, void* d_ws, size_t ws_size,
                              hipStream_t stream) {
    const float* z  = (const float*)d_in[0];
    const float* cb = (const float*)d_in[1];
    float* out = (float*)d_out;
    char* ws = (char*)d_ws;
    float*    cn     = (float*)(ws + WS_CN);
    __bf16*   cbh    = (__bf16*)(ws + WS_CBH);
    __bf16*   cbl    = (__bf16*)(ws + WS_CBL);
    int*      idx    = (int*)(ws + WS_IDX);
    unsigned* counts = (unsigned*)(ws + WS_COUNTS);
    float*    sse    = (float*)(ws + WS_SSE);

    hipMemsetAsync(ws + WS_COUNTS, 0, 4096 + 4, stream);
    prep_kernel<<<4, 256, 0, stream>>>(cb, cn, cbh, cbl);
    argmin_kernel<<<512, 256, 0, stream>>>(z, cbh, cbl, cn, idx);
    gather_kernel<<<2048, 256, 0, stream>>>(z, cb, idx, out, counts, sse);
    finalize_kernel<<<1, 256, 0, stream>>>(counts, sse, out);
}

// Round 4
// 179.705 us; speedup vs baseline: 2.3410x; 1.1106x over previous
//
#include <hip/hip_runtime.h>
#include <cfloat>
#include <cmath>

#define N_TOK (32*4096)                 // 131072 tokens
#define DIM   64
#define N_E   1024

typedef __attribute__((ext_vector_type(8))) __bf16 bf16x8;
typedef __attribute__((ext_vector_type(4))) float  f32x4;
typedef unsigned int u32;

// ws layout (bytes)
#define WS_CN2    0u                    // 1024 f32  (-0.5*||e||^2)          (4 KB)
#define WS_CBF    4096u                 // fragment-ordered bf16 hi+lo       (256 KB)
#define WS_IDX    266240u               // 131072 int                        (512 KB)
#define WS_COUNTS 790528u               // 1024 u32                          (4 KB)
#define WS_SSE    794624u               // 1 f32

// async global->LDS, 16 B per lane; LDS dest must be wave-uniform base + lane*16
__device__ __forceinline__ void async_cp16(const void* g, void* l) {
    __builtin_amdgcn_global_load_lds((const __attribute__((address_space(1))) u32*)g,
                                     (__attribute__((address_space(3))) u32*)l, 16, 0, 0);
}

// Emit codebook in MFMA B-fragment order (bf16 hi/lo split), per-128-code block:
//   cbF[cblk*16384 + plane*8192 + chunk*1024 + kf*512 + (q*16+n)*8 + j]
//     = plane_of( e[cblk*128 + chunk*16 + n][kf*32 + q*8 + j] )
// Also: cn2 = -0.5*||e||^2, and zero counts/sse (replaces a memset dispatch).
__global__ __launch_bounds__(256) void prep_kernel(const float* __restrict__ cb,
        float* __restrict__ cn2, __bf16* __restrict__ cbF,
        unsigned* __restrict__ counts, float* __restrict__ sse) {
    int k = blockIdx.x * 256 + threadIdx.x;          // 0..1023
    counts[k] = 0u;
    if (k == 0) *sse = 0.f;
    const float* row = cb + (size_t)k * DIM;
    const int cblk = k >> 7, local = k & 127;
    const int c = local >> 4, n = local & 15;
    __bf16* base = cbF + (size_t)cblk * 16384 + c * 1024 + n * 8;
    float nrm = 0.f;
#pragma unroll
    for (int kf = 0; kf < 2; ++kf) {
#pragma unroll
        for (int q = 0; q < 4; ++q) {
            float4 a = *(const float4*)(row + kf*32 + q*8);
            float4 b = *(const float4*)(row + kf*32 + q*8 + 4);
            float v[8] = {a.x,a.y,a.z,a.w,b.x,b.y,b.z,b.w};
            bf16x8 hv, lv;
#pragma unroll
            for (int j = 0; j < 8; ++j) {
                float f = v[j];
                nrm = fmaf(f, f, nrm);
                __bf16 h = (__bf16)f;
                __bf16 l = (__bf16)(f - (float)h);
                hv[j] = h; lv[j] = l;
            }
            *(bf16x8*)(base + kf*512 + q*128) = hv;
            *(bf16x8*)(base + 8192 + kf*512 + q*128) = lv;
        }
    }
    cn2[k] = -0.5f * nrm;
}

// argmax over (z.e - ||e||^2/2) == argmin distance. 3-pass bf16-split MFMA,
// cn folded into acc init, index packed into score low 10 mantissa bits.
__global__ __launch_bounds__(256, 2) void argmin_kernel(const float* __restrict__ z,
        const __bf16* __restrict__ cbF, const float* __restrict__ cn2,
        int* __restrict__ idx_out) {
    __shared__ __bf16 lbuf[16384];                   // 32 KB, fragment-ordered
    __shared__ float  lcn[128];
    const int t    = threadIdx.x;
    const int lane = t & 63;
    const int w    = t >> 6;
    const int n    = lane & 15;                      // MFMA col / code-in-chunk
    const int q    = lane >> 4;                      // k-octet selector
    const int wtok = blockIdx.x * 256 + w * 64;

    // A fragments (64 tokens/wave as 4 tiles x 2 K-halves), bf16 hi/lo in regs.
    bf16x8 ah[4][2], al[4][2];
    const float4* z4 = (const float4*)z;
#pragma unroll
    for (int tile = 0; tile < 4; ++tile) {
        int tok = wtok + tile*16 + n;
#pragma unroll
        for (int kf = 0; kf < 2; ++kf) {
            float4 p0 = z4[(size_t)tok*16 + kf*8 + q*2];
            float4 p1 = z4[(size_t)tok*16 + kf*8 + q*2 + 1];
            float v[8] = {p0.x,p0.y,p0.z,p0.w,p1.x,p1.y,p1.z,p1.w};
            bf16x8 hv, lv;
#pragma unroll
            for (int j = 0; j < 8; ++j) {
                __bf16 h = (__bf16)v[j];
                __bf16 l = (__bf16)(v[j] - (float)h);
                hv[j] = h; lv[j] = l;
            }
            ah[tile][kf] = hv; al[tile][kf] = lv;
        }
    }

    float best[16];
#pragma unroll
    for (int s = 0; s < 16; ++s) best[s] = -3.4e38f;

    for (int cblk = 0; cblk < 8; ++cblk) {
        __syncthreads();
        const __bf16* gsrc = cbF + (size_t)cblk * 16384;
#pragma unroll
        for (int i = 0; i < 8; ++i) {
            int off = (i*256 + t) * 16;              // bytes; lane-linear per wave
            async_cp16((const char*)gsrc + off, (char*)lbuf + off);
        }
        if (t < 128) lcn[t] = cn2[cblk*128 + t];
        __syncthreads();                             // drains vmcnt -> LDS ready

#pragma unroll 2
        for (int ch = 0; ch < 8; ++ch) {
            const int fb = ch*1024 + lane*8;         // conflict-free: lane*16 B
            bf16x8 bh0 = *(const bf16x8*)(lbuf + fb);
            bf16x8 bh1 = *(const bf16x8*)(lbuf + fb + 512);
            bf16x8 bl0 = *(const bf16x8*)(lbuf + fb + 8192);
            bf16x8 bl1 = *(const bf16x8*)(lbuf + fb + 8704);
            const float cnv = lcn[ch*16 + n];        // 4-way same-addr = broadcast
            const u32 codebits = (u32)(cblk*128 + ch*16 + n);
#pragma unroll
            for (int tile = 0; tile < 4; ++tile) {
                f32x4 acc = {cnv, cnv, cnv, cnv};
                acc = __builtin_amdgcn_mfma_f32_16x16x32_bf16(ah[tile][0], bh0, acc, 0, 0, 0);
                acc = __builtin_amdgcn_mfma_f32_16x16x32_bf16(ah[tile][1], bh1, acc, 0, 0, 0);
                acc = __builtin_amdgcn_mfma_f32_16x16x32_bf16(al[tile][0], bh0, acc, 0, 0, 0);
                acc = __builtin_amdgcn_mfma_f32_16x16x32_bf16(al[tile][1], bh1, acc, 0, 0, 0);
                acc = __builtin_amdgcn_mfma_f32_16x16x32_bf16(ah[tile][0], bl0, acc, 0, 0, 0);
                acc = __builtin_amdgcn_mfma_f32_16x16x32_bf16(ah[tile][1], bl1, acc, 0, 0, 0);
#pragma unroll
                for (int r = 0; r < 4; ++r) {
                    // v_and_or_b32 + v_max_f32: 2 ops/score
                    float packed = __uint_as_float((__float_as_uint(acc[r]) & 0xFFFFFC00u) | codebits);
                    best[tile*4 + r] = fmaxf(best[tile*4 + r], packed);
                }
            }
        }
    }

    // cross-lane argmax over the 16 code-columns; index rides in the low bits.
#pragma unroll
    for (int s = 0; s < 16; ++s) {
        float bs = best[s];
#pragma unroll
        for (int m = 8; m >= 1; m >>= 1)
            bs = fmaxf(bs, __shfl_xor(bs, m, 64));
        if (n == 0) {
            int tok = wtok + (s >> 2)*16 + q*4 + (s & 3);   // tile*16 + q*4 + r
            idx_out[tok] = (int)(__float_as_uint(bs) & 0x3FFu);
        }
    }
}

// Latency-optimized gather: wave owns 16 contiguous tokens; indices batch-loaded
// by lanes 0..15 in ONE instruction, broadcast via readlane -> all 32 row loads
// independent and in flight together. 8192 waves = 32 waves/CU.
__global__ __launch_bounds__(256) void gather_kernel(const float* __restrict__ z,
        const float* __restrict__ cb, const int* __restrict__ idx,
        float* __restrict__ out, unsigned* __restrict__ counts,
        float* __restrict__ sse) {
    const int lane = threadIdx.x & 63;
    const int w    = threadIdx.x >> 6;
    const int wid  = blockIdx.x * 4 + w;            // 0..8191
    const int base = wid * 16;

    int myidx = 0;
    if (lane < 16) myidx = idx[base + lane];

    float acc = 0.f;
#pragma unroll
    for (int i = 0; i < 16; ++i) {
        int id  = __shfl(myidx, i, 64);             // compile-time lane -> v_readlane
        int tok = base + i;
        float qv = cb[(size_t)id * DIM + lane];
        float zv = z[(size_t)tok * DIM + lane];
        out[1 + (size_t)tok * DIM + lane] = qv;
        float d = qv - zv;
        acc = fmaf(d, d, acc);
        if (lane == 0) atomicAdd(&counts[id], 1u);
    }
#pragma unroll
    for (int off = 32; off; off >>= 1) acc += __shfl_down(acc, off, 64);
    __shared__ float red[4];
    if (lane == 0) red[w] = acc;
    __syncthreads();
    if (threadIdx.x == 0) atomicAdd(sse, (red[0] + red[1]) + (red[2] + red[3]));
}

__global__ __launch_bounds__(256) void finalize_kernel(const unsigned* __restrict__ counts,
        const float* __restrict__ sse, float* __restrict__ out) {
    __shared__ float red[4];
    int t = threadIdx.x;
    float acc = 0.f;
#pragma unroll
    for (int i = 0; i < 4; ++i) {
        float p = (float)counts[t + 256*i] * (1.0f / 131072.0f);
        acc += p * logf(p + 1e-10f);
    }
#pragma unroll
    for (int off = 32; off; off >>= 1) acc += __shfl_down(acc, off, 64);
    if ((t & 63) == 0) red[t >> 6] = acc;
    __syncthreads();
    if (t == 0) {
        float H = -((red[0] + red[1]) + (red[2] + red[3]));
        out[0] = 1.25f * sse[0] * (1.0f / 8388608.0f);   // (1+BETA)*MSE
        out[8388609] = expf(H);
    }
}

extern "C" void kernel_launch(void* const* d_in, const int* in_sizes, int n_in,
                              void* d_out, int out_size, void* d_ws, size_t ws_size,
                              hipStream_t stream) {
    const float* z  = (const float*)d_in[0];
    const float* cb = (const float*)d_in[1];
    float* out = (float*)d_out;
    char* ws = (char*)d_ws;
    float*    cn2    = (float*)(ws + WS_CN2);
    __bf16*   cbF    = (__bf16*)(ws + WS_CBF);
    int*      idx    = (int*)(ws + WS_IDX);
    unsigned* counts = (unsigned*)(ws + WS_COUNTS);
    float*    sse    = (float*)(ws + WS_SSE);

    prep_kernel<<<4, 256, 0, stream>>>(cb, cn2, cbF, counts, sse);
    argmin_kernel<<<512, 256, 0, stream>>>(z, cbF, cn2, idx);
    gather_kernel<<<2048, 256, 0, stream>>>(z, cb, idx, out, counts, sse);
    finalize_kernel<<<1, 256, 0, stream>>>(counts, sse, out);
}

// Round 5
// 157.296 us; speedup vs baseline: 2.6745x; 1.1425x over previous
//
#include <hip/hip_runtime.h>
#include <cfloat>
#include <cmath>

#define N_TOK (32*4096)                 // 131072 tokens
#define DIM   64
#define N_E   1024

typedef __attribute__((ext_vector_type(8))) __bf16 bf16x8;
typedef __attribute__((ext_vector_type(4))) float  f32x4;
typedef unsigned int u32;

// ws layout (bytes)
#define WS_CN2    0u                    // 1024 f32  (-0.5*||e||^2)          (4 KB)
#define WS_CBF    4096u                 // fragment-ordered bf16 hi+lo       (256 KB)
#define WS_COUNTS 266240u               // 1024 u32                          (4 KB)
#define WS_SSE    270336u               // 1 f32

// async global->LDS, 16 B per lane; LDS dest must be wave-uniform base + lane*16
__device__ __forceinline__ void async_cp16(const void* g, void* l) {
    __builtin_amdgcn_global_load_lds((const __attribute__((address_space(1))) u32*)g,
                                     (__attribute__((address_space(3))) u32*)l, 16, 0, 0);
}

// Emit codebook in MFMA B-fragment order (bf16 hi/lo split), per-128-code block.
// Also: cn2 = -0.5*||e||^2, and zero counts/sse.
__global__ __launch_bounds__(256) void prep_kernel(const float* __restrict__ cb,
        float* __restrict__ cn2, __bf16* __restrict__ cbF,
        unsigned* __restrict__ counts, float* __restrict__ sse) {
    int k = blockIdx.x * 256 + threadIdx.x;          // 0..1023
    counts[k] = 0u;
    if (k == 0) *sse = 0.f;
    const float* row = cb + (size_t)k * DIM;
    const int cblk = k >> 7, local = k & 127;
    const int c = local >> 4, n = local & 15;
    __bf16* base = cbF + (size_t)cblk * 16384 + c * 1024 + n * 8;
    float nrm = 0.f;
#pragma unroll
    for (int kf = 0; kf < 2; ++kf) {
#pragma unroll
        for (int q = 0; q < 4; ++q) {
            float4 a = *(const float4*)(row + kf*32 + q*8);
            float4 b = *(const float4*)(row + kf*32 + q*8 + 4);
            float v[8] = {a.x,a.y,a.z,a.w,b.x,b.y,b.z,b.w};
            bf16x8 hv, lv;
#pragma unroll
            for (int j = 0; j < 8; ++j) {
                float f = v[j];
                nrm = fmaf(f, f, nrm);
                __bf16 h = (__bf16)f;
                __bf16 l = (__bf16)(f - (float)h);
                hv[j] = h; lv[j] = l;
            }
            *(bf16x8*)(base + kf*512 + q*128) = hv;
            *(bf16x8*)(base + 8192 + kf*512 + q*128) = lv;
        }
    }
    cn2[k] = -0.5f * nrm;
}

// Fused: argmax(z.e - ||e||^2/2) via 3-pass bf16-split MFMA (== argmin dist),
// then counts / SSE (from scores: d = ||z||^2 - 2*score) / z_q gather-write,
// all in one kernel. No idx round-trip, no z reload.
__global__ __launch_bounds__(256, 2) void fused_kernel(const float* __restrict__ z,
        const __bf16* __restrict__ cbF, const float* __restrict__ cn2,
        const float* __restrict__ cb, float* __restrict__ out,
        unsigned* __restrict__ counts, float* __restrict__ sse) {
    __shared__ __bf16 lbuf[16384];                   // 32 KB, fragment-ordered
    __shared__ float  lcn[128];
    __shared__ int    lidx[256];
    __shared__ float  lred[4];
    const int t    = threadIdx.x;
    const int lane = t & 63;
    const int w    = t >> 6;
    const int n    = lane & 15;                      // MFMA col / code-in-chunk
    const int q    = lane >> 4;                      // k-octet selector
    const int wtok = blockIdx.x * 256 + w * 64;

    // A fragments (64 tokens/wave as 4 tiles x 2 K-halves), bf16 hi/lo in regs.
    // pn[tile] = exact fp32 ||z||^2 of token wtok+tile*16+n (full 64 dims after q-reduce).
    bf16x8 ah[4][2], al[4][2];
    float pn[4];
    const float4* z4 = (const float4*)z;
#pragma unroll
    for (int tile = 0; tile < 4; ++tile) {
        int tok = wtok + tile*16 + n;
        float nrm = 0.f;
#pragma unroll
        for (int kf = 0; kf < 2; ++kf) {
            float4 p0 = z4[(size_t)tok*16 + kf*8 + q*2];
            float4 p1 = z4[(size_t)tok*16 + kf*8 + q*2 + 1];
            float v[8] = {p0.x,p0.y,p0.z,p0.w,p1.x,p1.y,p1.z,p1.w};
            bf16x8 hv, lv;
#pragma unroll
            for (int j = 0; j < 8; ++j) {
                float f = v[j];
                nrm = fmaf(f, f, nrm);
                __bf16 h = (__bf16)f;
                __bf16 l = (__bf16)(f - (float)h);
                hv[j] = h; lv[j] = l;
            }
            ah[tile][kf] = hv; al[tile][kf] = lv;
        }
        nrm += __shfl_xor(nrm, 16, 64);              // sum over q-group ->
        nrm += __shfl_xor(nrm, 32, 64);              // all 4 q-lanes hold full norm
        pn[tile] = nrm;
    }

    float best[16];
#pragma unroll
    for (int s = 0; s < 16; ++s) best[s] = -3.4e38f;

    for (int cblk = 0; cblk < 8; ++cblk) {
        __syncthreads();
        const __bf16* gsrc = cbF + (size_t)cblk * 16384;
#pragma unroll
        for (int i = 0; i < 8; ++i) {
            int off = (i*256 + t) * 16;              // bytes; lane-linear per wave
            async_cp16((const char*)gsrc + off, (char*)lbuf + off);
        }
        if (t < 128) lcn[t] = cn2[cblk*128 + t];
        __syncthreads();                             // drains vmcnt -> LDS ready

#pragma unroll 2
        for (int ch = 0; ch < 8; ++ch) {
            const int fb = ch*1024 + lane*8;         // conflict-free: lane*16 B
            bf16x8 bh0 = *(const bf16x8*)(lbuf + fb);
            bf16x8 bh1 = *(const bf16x8*)(lbuf + fb + 512);
            bf16x8 bl0 = *(const bf16x8*)(lbuf + fb + 8192);
            bf16x8 bl1 = *(const bf16x8*)(lbuf + fb + 8704);
            const float cnv = lcn[ch*16 + n];
            const u32 codebits = (u32)(cblk*128 + ch*16 + n);
#pragma unroll
            for (int tile = 0; tile < 4; ++tile) {
                f32x4 acc = {cnv, cnv, cnv, cnv};
                acc = __builtin_amdgcn_mfma_f32_16x16x32_bf16(ah[tile][0], bh0, acc, 0, 0, 0);
                acc = __builtin_amdgcn_mfma_f32_16x16x32_bf16(ah[tile][1], bh1, acc, 0, 0, 0);
                acc = __builtin_amdgcn_mfma_f32_16x16x32_bf16(al[tile][0], bh0, acc, 0, 0, 0);
                acc = __builtin_amdgcn_mfma_f32_16x16x32_bf16(al[tile][1], bh1, acc, 0, 0, 0);
                acc = __builtin_amdgcn_mfma_f32_16x16x32_bf16(ah[tile][0], bl0, acc, 0, 0, 0);
                acc = __builtin_amdgcn_mfma_f32_16x16x32_bf16(ah[tile][1], bl1, acc, 0, 0, 0);
#pragma unroll
                for (int r = 0; r < 4; ++r) {
                    float packed = __uint_as_float((__float_as_uint(acc[r]) & 0xFFFFFC00u) | codebits);
                    best[tile*4 + r] = fmaxf(best[tile*4 + r], packed);
                }
            }
        }
    }

    // cross-lane argmax per slot; winner idx -> LDS; counts + SSE on n==0 lanes.
    float sse_acc = 0.f;
#pragma unroll
    for (int s = 0; s < 16; ++s) {
        float bs = best[s];
#pragma unroll
        for (int m = 8; m >= 1; m >>= 1)
            bs = fmaxf(bs, __shfl_xor(bs, m, 64));
        u32 bits = __float_as_uint(bs);
        int id = (int)(bits & 0x3FFu);
        float sc = __uint_as_float(bits & 0xFFFFFC00u);
        // norm of token tile*16 + q*4 + r lives in lane (q*4+r) of the n-dim (q''=0)
        float nrm = __shfl(pn[s >> 2], (q << 2) | (s & 3), 64);
        if (n == 0) {
            lidx[w*64 + (s >> 2)*16 + q*4 + (s & 3)] = id;
            atomicAdd(&counts[id], 1u);
            sse_acc += fmaf(-2.f, sc, nrm);          // d = ||z||^2 - 2*score
        }
    }
    // wave SSE reduce (nonzero only on lanes 0,16,32,48) -> block -> global
    sse_acc += __shfl_xor(sse_acc, 16, 64);
    sse_acc += __shfl_xor(sse_acc, 32, 64);
    if (lane == 0) lred[w] = sse_acc;
    __syncthreads();
    if (t == 0) atomicAdd(sse, (lred[0] + lred[1]) + (lred[2] + lred[3]));

    // z_q write phase: wave writes its own 64 tokens, gather-style
    // (readlane id -> SGPR base -> 64 independent coalesced row loads+stores).
    int myid = lidx[w*64 + lane];
    const size_t obase = 1 + (size_t)wtok * DIM;
#pragma unroll
    for (int i = 0; i < 64; ++i) {
        int id = __shfl(myid, i, 64);                // compile-time lane -> v_readlane
        float qv = cb[(size_t)id * DIM + lane];
        out[obase + (size_t)i * DIM + lane] = qv;
    }
}

__global__ __launch_bounds__(256) void finalize_kernel(const unsigned* __restrict__ counts,
        const float* __restrict__ sse, float* __restrict__ out) {
    __shared__ float red[4];
    int t = threadIdx.x;
    float acc = 0.f;
#pragma unroll
    for (int i = 0; i < 4; ++i) {
        float p = (float)counts[t + 256*i] * (1.0f / 131072.0f);
        acc += p * logf(p + 1e-10f);
    }
#pragma unroll
    for (int off = 32; off; off >>= 1) acc += __shfl_down(acc, off, 64);
    if ((t & 63) == 0) red[t >> 6] = acc;
    __syncthreads();
    if (t == 0) {
        float H = -((red[0] + red[1]) + (red[2] + red[3]));
        out[0] = 1.25f * sse[0] * (1.0f / 8388608.0f);   // (1+BETA)*MSE
        out[8388609] = expf(H);
    }
}

extern "C" void kernel_launch(void* const* d_in, const int* in_sizes, int n_in,
                              void* d_out, int out_size, void* d_ws, size_t ws_size,
                              hipStream_t stream) {
    const float* z  = (const float*)d_in[0];
    const float* cb = (const float*)d_in[1];
    float* out = (float*)d_out;
    char* ws = (char*)d_ws;
    float*    cn2    = (float*)(ws + WS_CN2);
    __bf16*   cbF    = (__bf16*)(ws + WS_CBF);
    unsigned* counts = (unsigned*)(ws + WS_COUNTS);
    float*    sse    = (float*)(ws + WS_SSE);

    prep_kernel<<<4, 256, 0, stream>>>(cb, cn2, cbF, counts, sse);
    fused_kernel<<<512, 256, 0, stream>>>(z, cbF, cn2, cb, out, counts, sse);
    finalize_kernel<<<1, 256, 0, stream>>>(counts, sse, out);
}